// Round 12
// baseline (31.849 us; speedup 1.0000x reference)
//
#include <hip/hip_runtime.h>
#include <hip/hip_bf16.h>
#include <math.h>

// Engram scan. Fast path: prove on-device that every step is a "create"
// (feedback == 0) and write zeros; exact sequential fallback otherwise.
//
// Soundness: n0==0 & B<=P => bank holds verbatim copies of earlier padrao
// rows and n<P always => every step creates unless a cos>=0.7 match exists
// among pairs (t, j<t). We flag at cos_q>=0.5 computed in fp8-e4m3 (RNE
// rel-err <=2^-4 => |cos_q-cos| <= ~0.135 with fp32 norms; 0.7-0.135 >
// 0.5 => conservative superset). Rows with any |x|>224 (e4m3 saturation)
// force the fallback via flag. Flag also set if n0!=0 or B>P. Threshold is
// applied in squared form (acc>0 && acc^2 >= 0.25*pn2_t*pn2_j). MFMA
// C-layout = m89 mapping; layout errors fail-safe (false flag -> fallback).
//
// r12 (r11 swizzle null => not L3-BW; budget audit vs r1 calibration):
//  1. k_prep was ~8-10us: one block per row + interleaved packed layout
//     => each lane stored 4B at 256B stride (zero write coalescing).
//     Now PANEL prep: block = 16 rows, packs via 16KB LDS tile, dumps the
//     panel contiguously (fully coalesced). Norms kept squared (pn2).
//  2. k_trimain ~11us latency floor: runtime-trip loop => no cross-
//     superstep prefetch => ~200cy L2 latency serialized per superstep at
//     2 waves/SIMD. Now register double-buffer: issue s+1's 5 loads before
//     s's 8 MFMAs (one superstep of hiding); nss compile-time (D=1024).

#define LIMIAR_SIM 0.7f
#define LIMIAR_NOVO 0.3f
#define LR 0.01f
#define EPSV 1e-8f
#define CHECK_T2 0.25f      // (0.5)^2 conservative vs 0.7 decision threshold
#define ABS_GUARD 224.0f    // |x| above this -> fp8 bound unsafe -> fallback

typedef __attribute__((ext_vector_type(4))) float f32x4;
typedef __attribute__((ext_vector_type(2))) long long i64x2;

// -- kernel 1 (fast path): panel prep. block = 16-row panel.
// coalesced read -> fp8 pack via LDS -> coalesced 16KB panel dump;
// squared norms; nt zero-fill of this panel's d_out slice; amax guard.
// D hardcoded 1024 (gated in kernel_launch).
__global__ __launch_bounds__(256) void k_prep_panel(const float* __restrict__ padrao,
                                                    int B, float* __restrict__ pn2,
                                                    unsigned int* __restrict__ xq,
                                                    f32x4* __restrict__ out4,
                                                    unsigned int* __restrict__ flag,
                                                    const int* __restrict__ n0p,
                                                    int force_flag) {
    __shared__ unsigned int lpk[4096];   // 16 rows x 1024 fp8 = 16KB
    __shared__ float rp[16][4];
    __shared__ float ram[16][4];
    int p = blockIdx.x;
    int r0 = p << 4;
    int t = threadIdx.x;
    int wid = t >> 6, lane = t & 63;
    // ---- nt zero-fill: this panel's d_out slice (4096 f32x4) ----
    {
        f32x4 z = {0.f, 0.f, 0.f, 0.f};
        long long zb = (long long)p * 4096;
#pragma unroll
        for (int i = 0; i < 16; ++i)
            __builtin_nontemporal_store(z, &out4[zb + i * 256 + t]);
    }
    // ---- read 16 rows coalesced; norms + amax + pack into LDS ----
    int k = t * 4;
    int c = k >> 3, ssl = c >> 3, j = c & 7;
    int slot = (ssl << 3) + ((j & 3) << 1) + (j >> 2);
    int su = slot >> 1, h = slot & 1;
    int lbase = (su * 16) * 4 + h * 2 + ((k >> 2) & 1);
    for (int i = 0; i < 16; ++i) {
        float4 v = *(const float4*)(padrao + ((long long)(r0 + i) << 10) + k);
        float ss = v.x * v.x + v.y * v.y + v.z * v.z + v.w * v.w;
        float am = fmaxf(fmaxf(fabsf(v.x), fabsf(v.y)),
                         fmaxf(fabsf(v.z), fabsf(v.w)));
        for (int off = 32; off > 0; off >>= 1) {
            ss += __shfl_down(ss, off);
            am = fmaxf(am, __shfl_down(am, off));
        }
        if (lane == 0) { rp[i][wid] = ss; ram[i][wid] = am; }
        int pk = 0;
        pk = __builtin_amdgcn_cvt_pk_fp8_f32(v.x, v.y, pk, false);
        pk = __builtin_amdgcn_cvt_pk_fp8_f32(v.z, v.w, pk, true);
        lpk[lbase + i * 4] = (unsigned int)pk;
    }
    __syncthreads();
    // ---- coalesced panel dump: 1024 uint4 ----
    {
        const uint4* lp4 = (const uint4*)lpk;
        uint4* gq4 = (uint4*)(xq + ((long long)p << 12));
#pragma unroll
        for (int i = 0; i < 4; ++i)
            gq4[i * 256 + t] = lp4[i * 256 + t];
    }
    // ---- squared norms + guard ----
    if (t < 16) {
        float tot = rp[t][0] + rp[t][1] + rp[t][2] + rp[t][3];
        pn2[r0 + t] = fmaxf(tot, 1e-16f);
    }
    if (t == 0) {
        float bm = 0.0f;
        for (int i = 0; i < 16; ++i)
            for (int wv = 0; wv < 4; ++wv) bm = fmaxf(bm, ram[i][wv]);
        unsigned int f = 0;
        if (bm > ABS_GUARD) f = 1u;
        if (p == 0 && (force_flag || (*n0p != 0))) f = 1u;
        if (f) atomicOr(flag, 1u);
    }
}

// ------- kernel 2: fp8 MFMA tri-check, M-split, reg double-buffer -------
// 64x64 tile/block, 4 waves; wave w owns rows [r0+16w,+16) over K=1024.
// Superstep s (K=64): 1 A + 4 B 16B loads -> 8 fp8 MFMAs. Next superstep's
// loads issued BEFORE this superstep's MFMAs (latency hiding).
__global__ __launch_bounds__(256) void k_trimain(const unsigned int* __restrict__ xq,
                                                 const float* __restrict__ pn2,
                                                 int B,
                                                 unsigned int* __restrict__ flag) {
    // T1 bijective XCD swizzle (kept from r11; neutral-to-positive)
    int nblk = gridDim.x;
    int orig = blockIdx.x;
    int q8 = nblk >> 3, r8 = nblk & 7;
    int xcd = orig & 7, lin = orig >> 3;
    int bid = (xcd < r8 ? xcd * (q8 + 1) : r8 * (q8 + 1) + (xcd - r8) * q8) + lin;
    int ti = (int)((sqrtf(8.0f * (float)bid + 1.0f) - 1.0f) * 0.5f);
    while ((ti + 1) * (ti + 2) / 2 <= bid) ++ti;
    while (ti * (ti + 1) / 2 > bid) --ti;
    int tj = bid - ti * (ti + 1) / 2;
    int r0 = ti * 64, c0 = tj * 64;
    int tid = threadIdx.x;
    int w = tid >> 6, l = tid & 63;
    int l15 = l & 15, lhi = l >> 4;
    const int kchu = 64;                    // 1024/16 : 16B units per panel
    const i64x2* gx = (const i64x2*)xq;
    long long rpan = (long long)((r0 >> 4) + w) * kchu;
    long long cp0 = (long long)(c0 >> 4) * kchu;
    long long cp1 = cp0 + kchu, cp2 = cp1 + kchu, cp3 = cp2 + kchu;
    f32x4 acc0 = {}, acc1 = {}, acc2 = {}, acc3 = {};
    const int nss = 16;                     // supersteps (K=64 each)
    int uc = lhi;
    i64x2 a0 = gx[(rpan + uc) * 16 + l15];
    i64x2 b0 = gx[(cp0 + uc) * 16 + l15];
    i64x2 b1 = gx[(cp1 + uc) * 16 + l15];
    i64x2 b2 = gx[(cp2 + uc) * 16 + l15];
    i64x2 b3 = gx[(cp3 + uc) * 16 + l15];
    for (int s = 0; s < nss - 1; ++s) {
        int un = ((s + 1) << 2) + lhi;
        i64x2 an = gx[(rpan + un) * 16 + l15];
        i64x2 bn0 = gx[(cp0 + un) * 16 + l15];
        i64x2 bn1 = gx[(cp1 + un) * 16 + l15];
        i64x2 bn2 = gx[(cp2 + un) * 16 + l15];
        i64x2 bn3 = gx[(cp3 + un) * 16 + l15];
        acc0 = __builtin_amdgcn_mfma_f32_16x16x32_fp8_fp8(a0[0], b0[0], acc0, 0, 0, 0);
        acc0 = __builtin_amdgcn_mfma_f32_16x16x32_fp8_fp8(a0[1], b0[1], acc0, 0, 0, 0);
        acc1 = __builtin_amdgcn_mfma_f32_16x16x32_fp8_fp8(a0[0], b1[0], acc1, 0, 0, 0);
        acc1 = __builtin_amdgcn_mfma_f32_16x16x32_fp8_fp8(a0[1], b1[1], acc1, 0, 0, 0);
        acc2 = __builtin_amdgcn_mfma_f32_16x16x32_fp8_fp8(a0[0], b2[0], acc2, 0, 0, 0);
        acc2 = __builtin_amdgcn_mfma_f32_16x16x32_fp8_fp8(a0[1], b2[1], acc2, 0, 0, 0);
        acc3 = __builtin_amdgcn_mfma_f32_16x16x32_fp8_fp8(a0[0], b3[0], acc3, 0, 0, 0);
        acc3 = __builtin_amdgcn_mfma_f32_16x16x32_fp8_fp8(a0[1], b3[1], acc3, 0, 0, 0);
        a0 = an; b0 = bn0; b1 = bn1; b2 = bn2; b3 = bn3;
    }
    acc0 = __builtin_amdgcn_mfma_f32_16x16x32_fp8_fp8(a0[0], b0[0], acc0, 0, 0, 0);
    acc0 = __builtin_amdgcn_mfma_f32_16x16x32_fp8_fp8(a0[1], b0[1], acc0, 0, 0, 0);
    acc1 = __builtin_amdgcn_mfma_f32_16x16x32_fp8_fp8(a0[0], b1[0], acc1, 0, 0, 0);
    acc1 = __builtin_amdgcn_mfma_f32_16x16x32_fp8_fp8(a0[1], b1[1], acc1, 0, 0, 0);
    acc2 = __builtin_amdgcn_mfma_f32_16x16x32_fp8_fp8(a0[0], b2[0], acc2, 0, 0, 0);
    acc2 = __builtin_amdgcn_mfma_f32_16x16x32_fp8_fp8(a0[1], b2[1], acc2, 0, 0, 0);
    acc3 = __builtin_amdgcn_mfma_f32_16x16x32_fp8_fp8(a0[0], b3[0], acc3, 0, 0, 0);
    acc3 = __builtin_amdgcn_mfma_f32_16x16x32_fp8_fp8(a0[1], b3[1], acc3, 0, 0, 0);
    // threshold on registers (squared); C layout (m89): col=l&15, row=lhi*4+r
    int trow = r0 + w * 16 + lhi * 4;
    float pnr[4];
#pragma unroll
    for (int r = 0; r < 4; ++r) {
        int t = trow + r;
        pnr[r] = (t < B) ? pn2[t] : 1.0f;
    }
    unsigned int hit = 0;
#pragma unroll
    for (int j = 0; j < 4; ++j) {
        int jj = c0 + j * 16 + l15;
        float pc = (jj < B) ? pn2[jj] : 1.0f;
        f32x4 av = (j == 0) ? acc0 : (j == 1) ? acc1 : (j == 2) ? acc2 : acc3;
#pragma unroll
        for (int r = 0; r < 4; ++r) {
            int t = trow + r;
            float a = av[r];
            if (t < B && jj < B && t > jj && a > 0.0f &&
                a * a >= CHECK_T2 * pnr[r] * pc)
                hit = 1;
        }
    }
    if (hit) atomicOr(flag, 1u);
}

// ---- ragged-path kernels (any shape; correct but not perf-critical) ----
__global__ __launch_bounds__(256) void k_norms_row(const float* __restrict__ padrao,
                                                   int B, int D, float* __restrict__ pn2,
                                                   unsigned int* __restrict__ flag,
                                                   const int* __restrict__ n0p,
                                                   int force_flag) {
    __shared__ float red[4];
    int row = blockIdx.x;
    const float* r = padrao + (long long)row * D;
    float s = 0.0f;
    for (int k = threadIdx.x; k < D; k += 256) { float v = r[k]; s += v * v; }
    for (int off = 32; off > 0; off >>= 1) s += __shfl_down(s, off);
    int wid = threadIdx.x >> 6, lane = threadIdx.x & 63;
    if (lane == 0) red[wid] = s;
    __syncthreads();
    if (threadIdx.x == 0) {
        pn2[row] = fmaxf(red[0] + red[1] + red[2] + red[3], 1e-16f);
        if (row == 0 && (force_flag || (*n0p != 0))) atomicOr(flag, 1u);
    }
}

__global__ __launch_bounds__(256) void k_tricheck(const float* __restrict__ padrao,
                                                  const float* __restrict__ pn2,
                                                  int B, int D,
                                                  unsigned int* __restrict__ flag) {
    __shared__ float As[64][65];
    __shared__ float Bs[64][65];
    int bid = blockIdx.x;
    int ti = (int)((sqrtf(8.0f * (float)bid + 1.0f) - 1.0f) * 0.5f);
    while ((ti + 1) * (ti + 2) / 2 <= bid) ++ti;
    while (ti * (ti + 1) / 2 > bid) --ti;
    int tj = bid - ti * (ti + 1) / 2;
    int r0 = ti * 64, c0 = tj * 64;
    int tid = threadIdx.x;
    int ty = tid >> 4, tx = tid & 15;
    float acc[4][4] = {};
    for (int k0 = 0; k0 < D; k0 += 64) {
        for (int s = tid; s < 64 * 64; s += 256) {
            int rr = s >> 6, cc = s & 63;
            int gc = k0 + cc;
            int gr = r0 + rr;
            As[rr][cc] = (gr < B && gc < D) ? padrao[(long long)gr * D + gc] : 0.0f;
            gr = c0 + rr;
            Bs[rr][cc] = (gr < B && gc < D) ? padrao[(long long)gr * D + gc] : 0.0f;
        }
        __syncthreads();
        for (int kk = 0; kk < 64; ++kk) {
            float a[4], b[4];
#pragma unroll
            for (int i = 0; i < 4; ++i) a[i] = As[ty * 4 + i][kk];
#pragma unroll
            for (int j = 0; j < 4; ++j) b[j] = Bs[tx * 4 + j][kk];
#pragma unroll
            for (int i = 0; i < 4; ++i)
#pragma unroll
                for (int j = 0; j < 4; ++j) acc[i][j] += a[i] * b[j];
        }
        __syncthreads();
    }
    unsigned int hit = 0;
    for (int i = 0; i < 4; ++i)
        for (int j = 0; j < 4; ++j) {
            int t = r0 + ty * 4 + i, jj = c0 + tx * 4 + j;
            if (t < B && jj < B && t > jj) {
                float a = acc[i][j];
                if (a > 0.0f && a * a >= CHECK_T2 * pn2[t] * pn2[jj]) hit = 1;
            }
        }
    if (hit) atomicOr(flag, 1u);
}

__global__ __launch_bounds__(256) void k_zero_s(float* __restrict__ out, long long n) {
    long long i = (long long)blockIdx.x * blockDim.x + threadIdx.x;
    long long stride = (long long)gridDim.x * blockDim.x;
    for (; i < n; i += stride) out[i] = 0.0f;
}

// ------- kernel 3: exact sequential fallback (runs only if flag set) -------
__global__ __launch_bounds__(1024) void k_fallback(
    const float* __restrict__ padrao, const float* __restrict__ erro,
    const float* __restrict__ protos0, const float* __restrict__ forca0,
    const int* __restrict__ n0p, const float* __restrict__ gainp,
    float* __restrict__ out, const float* __restrict__ pn2_arr,
    float* __restrict__ wprotos, float* __restrict__ wforca,
    float* __restrict__ wprotn, const unsigned int* __restrict__ flag,
    int runnable, int B, int D, int P) {
    if (!runnable) return;
    if (*flag == 0) return;
    const int tid = threadIdx.x;
    const int NT = blockDim.x;
    __shared__ float rv[1024];
    __shared__ int ri[1024];
    for (long long i = tid; i < (long long)P * D; i += NT) wprotos[i] = protos0[i];
    for (int i = tid; i < P; i += NT) wforca[i] = forca0[i];
    __syncthreads();
    for (int j = tid; j < P; j += NT) {
        const float* r = wprotos + (long long)j * D;
        float s = 0.0f;
        for (int k = 0; k < D; ++k) s += r[k] * r[k];
        wprotn[j] = fmaxf(sqrtf(s), EPSV);
    }
    int n = *n0p;
    float gain = *gainp;
    __syncthreads();
    for (int t = 0; t < B; ++t) {
        const float* p = padrao + (long long)t * D;
        float pn = fmaxf(sqrtf(pn2_arr[t]), EPSV);
        float best = -INFINITY; int bidx = 0;
        for (int j = tid; j < n; j += NT) {
            const float* r = wprotos + (long long)j * D;
            float d = 0.0f;
            for (int k = 0; k < D; ++k) d += r[k] * p[k];
            float sim = d / (wprotn[j] * pn);
            if (sim > best) { best = sim; bidx = j; }
        }
        rv[tid] = best; ri[tid] = bidx;
        __syncthreads();
        for (int off = NT >> 1; off > 0; off >>= 1) {
            if (tid < off) {
                float ov = rv[tid + off]; int oi = ri[tid + off];
                if (ov > rv[tid] || (ov == rv[tid] && oi < ri[tid])) { rv[tid] = ov; ri[tid] = oi; }
            }
            __syncthreads();
        }
        float max_sim = rv[0]; int idx = ri[0];
        __syncthreads();
        float err = erro[t];
        bool is_empty = (n == 0);
        bool do_reinf = (!is_empty) && (max_sim >= LIMIAR_SIM);
        bool do_create = is_empty || ((!do_reinf) && ((err > LIMIAR_NOVO) || (n < P)));
        if (do_create) {
            int cidx = n;
            if (n >= P) {
                float bv = INFINITY; int bi = 0;
                for (int j = tid; j < P; j += NT) {
                    float f = wforca[j];
                    if (f < bv) { bv = f; bi = j; }
                }
                rv[tid] = bv; ri[tid] = bi;
                __syncthreads();
                for (int off = NT >> 1; off > 0; off >>= 1) {
                    if (tid < off) {
                        float ov = rv[tid + off]; int oi = ri[tid + off];
                        if (ov < rv[tid] || (ov == rv[tid] && oi < ri[tid])) { rv[tid] = ov; ri[tid] = oi; }
                    }
                    __syncthreads();
                }
                cidx = ri[0];
                __syncthreads();
            }
            float* dst = wprotos + (long long)cidx * D;
            float* o = out + (long long)t * D;
            for (int k = tid; k < D; k += NT) { dst[k] = p[k]; o[k] = 0.0f; }
            if (tid == 0) { wforca[cidx] = 1.0f; wprotn[cidx] = pn; }
            if (n < P) n = n + 1;
        } else if (do_reinf) {
            float* dst = wprotos + (long long)idx * D;
            float fr_new = wforca[idx] + LR;
            float* o = out + (long long)t * D;
            float s2 = 0.0f;
            for (int k = tid; k < D; k += NT) {
                float np_ = (1.0f - LR) * dst[k] + LR * p[k];
                dst[k] = np_;
                o[k] = (np_ - p[k]) * fr_new * gain;
                s2 += np_ * np_;
            }
            rv[tid] = s2;
            __syncthreads();
            for (int off = NT >> 1; off > 0; off >>= 1) {
                if (tid < off) rv[tid] += rv[tid + off];
                __syncthreads();
            }
            if (tid == 0) { wforca[idx] = fr_new; wprotn[idx] = fmaxf(sqrtf(rv[0]), EPSV); }
        } else {
            const float* src = wprotos + (long long)idx * D;
            float fr = wforca[idx];
            float* o = out + (long long)t * D;
            for (int k = tid; k < D; k += NT) o[k] = (src[k] - p[k]) * fr * gain;
        }
        __syncthreads();
    }
}

extern "C" void kernel_launch(void* const* d_in, const int* in_sizes, int n_in,
                              void* d_out, int out_size, void* d_ws, size_t ws_size,
                              hipStream_t stream) {
    const float* padrao  = (const float*)d_in[0];
    const float* erro    = (const float*)d_in[1];
    const float* protos0 = (const float*)d_in[2];
    const float* forca0  = (const float*)d_in[3];
    const int*   n0p     = (const int*)d_in[5];
    const float* gainp   = (const float*)d_in[6];
    const int B = in_sizes[1];
    const int D = (B > 0) ? in_sizes[0] / B : 0;
    const int P = in_sizes[3];

    char* ws = (char*)d_ws;
    unsigned int* flag = (unsigned int*)ws;
    float* pn2 = (float*)(ws + 64);
    size_t off_xq = ((64 + (size_t)B * 4) + 63) & ~(size_t)63;
    unsigned int* xq = (unsigned int*)(ws + off_xq);
    size_t off_protos = (off_xq + (size_t)B * (size_t)D + 63) & ~(size_t)63;  // fp8: B*D bytes
    float* wprotos = (float*)(ws + off_protos);
    size_t off_forca = off_protos + (size_t)P * (size_t)D * 4;
    float* wforca = (float*)(ws + off_forca);
    size_t off_protn = off_forca + (size_t)P * 4;
    float* wprotn = (float*)(ws + off_protn);
    size_t need_total = off_protn + (size_t)P * 4;
    size_t need_fast = off_xq + (size_t)B * (size_t)D;

    int runnable = (ws_size >= need_total) ? 1 : 0;
    int force_flag = (B > P) ? 1 : 0;
    int use_mfma = ((B % 64) == 0) && (D == 1024) && (ws_size >= need_fast)
                   && ((long long)out_size == (long long)B * D);

    int nT = (B + 63) / 64;
    int nblk = nT * (nT + 1) / 2;
    long long outN = (long long)out_size;

    // flag = 0 (prep/trimain only OR into it; async memset is capture-safe)
    hipMemsetAsync(flag, 0, sizeof(unsigned int), stream);

    if (use_mfma) {
        k_prep_panel<<<B / 16, 256, 0, stream>>>(padrao, B, pn2, xq,
                                                 (f32x4*)d_out, flag, n0p, force_flag);
        k_trimain<<<nblk, 256, 0, stream>>>(xq, pn2, B, flag);
    } else {
        k_norms_row<<<B, 256, 0, stream>>>(padrao, B, D, pn2, flag, n0p, force_flag);
        k_tricheck<<<nblk, 256, 0, stream>>>(padrao, pn2, B, D, flag);
        int zb = (int)((outN + 255) / 256); if (zb > 2048) zb = 2048; if (zb < 1) zb = 1;
        k_zero_s<<<zb, 256, 0, stream>>>((float*)d_out, outN);
    }

    k_fallback<<<1, 1024, 0, stream>>>(padrao, erro, protos0, forca0, n0p, gainp,
                                       (float*)d_out, pn2, wprotos, wforca, wprotn,
                                       flag, runnable, B, D, P);
}

// Round 13
// 27.805 us; speedup vs baseline: 1.1454x; 1.1454x over previous
//
#include <hip/hip_runtime.h>
#include <hip/hip_bf16.h>
#include <math.h>

// Engram scan. Fast path: prove on-device that every step is a "create"
// (feedback == 0) and write zeros; exact sequential fallback otherwise.
//
// Soundness: n0==0 & B<=P => bank holds verbatim copies of earlier padrao
// rows and n<P always => every step creates unless a cos>=0.7 match exists
// among pairs (t, j<t). We flag at cos_q>=0.5 computed in fp8-e4m3 (RNE
// rel-err <=2^-4 => |cos_q-cos| <= ~0.135 with fp32 norms; 0.7-0.135 >
// 0.5 => conservative superset). Rows with any |x|>224 (e4m3 saturation)
// force the fallback via flag. Flag also set if n0!=0 or B>P. Threshold is
// applied in squared form (acc>0 && acc^2 >= 0.25*pn2_t*pn2_j). MFMA
// C-layout = m89 mapping; layout errors fail-safe (false flag -> fallback).
//
// r13 (r12 = +5.5us regression, confounded double-change; reverted):
//  * k_trimain: EXACT r11 structure (26.3us known-good): M-split, runtime
//    k-loop, XCD swizzle, no manual prefetch. (r12 model: L1/TA issue-BW
//    bound -> prefetch null, as measured.)
//  * k_prep: ONLY change this round. r12's 128-block panel prep halved CU
//    utilization (0.5 blocks/CU). Now block = (panel, 256-float chunk):
//    512 blocks (2/CU), coalesced 16KB read, 4KB LDS stage, fully
//    coalesced 4KB dump (one ss superslot = contiguous 1KB in the packed
//    layout). Norms via wave-shuffle partials + atomicAdd into memset pn2.

#define LIMIAR_SIM 0.7f
#define LIMIAR_NOVO 0.3f
#define LR 0.01f
#define EPSV 1e-8f
#define CHECK_T2 0.25f      // (0.5)^2 conservative vs 0.7 decision threshold
#define ABS_GUARD 224.0f    // |x| above this -> fp8 bound unsafe -> fallback

typedef __attribute__((ext_vector_type(4))) float f32x4;
typedef __attribute__((ext_vector_type(2))) long long i64x2;

// -- kernel 1 (fast path): chunk prep. block = (16-row panel, 256-float k-chunk).
// 512 blocks for B=2048. Coalesced read; fp8 pack via 4KB LDS; coalesced
// contiguous dump; wave-partial norms -> atomicAdd(pn2); amax guard; nt
// zero-fill of this block's d_out slice. D hardcoded 1024 (gated).
__global__ __launch_bounds__(256) void k_prep_chunk(const float* __restrict__ padrao,
                                                    int B, float* __restrict__ pn2,
                                                    unsigned int* __restrict__ xq,
                                                    f32x4* __restrict__ out4,
                                                    unsigned int* __restrict__ flag,
                                                    const int* __restrict__ n0p,
                                                    int force_flag) {
    __shared__ unsigned int lpk[1024];   // 16 su x 16 rows x 4 u32 = 4KB
    int blk = blockIdx.x;
    int p = blk >> 2, cb = blk & 3;      // panel, k-chunk (256 floats)
    int r0 = p << 4;
    int t = threadIdx.x;
    int lane = t & 63;
    // ---- nt zero-fill: this block's d_out slice (1024 f32x4) ----
    {
        f32x4 z = {0.f, 0.f, 0.f, 0.f};
        long long zb = (long long)blk * 1024;
#pragma unroll
        for (int i = 0; i < 4; ++i)
            __builtin_nontemporal_store(z, &out4[zb + i * 256 + t]);
    }
    if (blk == 0 && t == 0 && (force_flag || (*n0p != 0))) atomicOr(flag, 1u);
    // ---- per-lane k position & packed-layout address (fixed per thread) ----
    int k = (cb << 8) + (lane << 2);     // this lane's 4 floats within the row
    int c = k >> 3, ssv = c >> 3, j = c & 7;
    int slot = (ssv << 3) + ((j & 3) << 1) + (j >> 2);
    int su_rel = (slot >> 1) - (cb << 4);   // in [0,16)
    int lidx = (su_rel << 6) + ((slot & 1) << 1) + (lane & 1);  // + row*4 later
    int wrow = t >> 6;                   // wave id -> row offset within pass
    // ---- 4 passes x 4 rows: read, reduce, pack ----
    for (int pass = 0; pass < 4; ++pass) {
        int i = (pass << 2) + wrow;      // row 0..15
        float4 v = *(const float4*)(padrao + ((long long)(r0 + i) << 10) + k);
        float ss = v.x * v.x + v.y * v.y + v.z * v.z + v.w * v.w;
        float am = fmaxf(fmaxf(fabsf(v.x), fabsf(v.y)),
                         fmaxf(fabsf(v.z), fabsf(v.w)));
        for (int off = 32; off > 0; off >>= 1) ss += __shfl_down(ss, off);
        if (lane == 0) atomicAdd(&pn2[r0 + i], ss);
        if (__any(am > ABS_GUARD) && lane == 0) atomicOr(flag, 1u);
        int pk = 0;
        pk = __builtin_amdgcn_cvt_pk_fp8_f32(v.x, v.y, pk, false);
        pk = __builtin_amdgcn_cvt_pk_fp8_f32(v.z, v.w, pk, true);
        lpk[lidx + i * 4] = (unsigned int)pk;
    }
    __syncthreads();
    // ---- coalesced dump: 256 uint4 contiguous ----
    {
        const uint4* lp4 = (const uint4*)lpk;
        uint4* gq4 = (uint4*)xq + ((long long)p * 1024 + (cb << 8));
        gq4[t] = lp4[t];
    }
}

// ------- kernel 2: fp8 MFMA tri-check (EXACT r11 structure, squared thr) -------
// 64x64 tile/block, 4 waves; wave w owns rows [r0+16w,+16) over full K.
// Superstep s (K=64): 1 A + 4 B 16B loads -> 8 fp8 MFMAs (K=32 each).
__global__ __launch_bounds__(256) void k_trimain(const unsigned int* __restrict__ xq,
                                                 const float* __restrict__ pn2,
                                                 int B, int D,
                                                 unsigned int* __restrict__ flag) {
    // T1 bijective XCD swizzle (m204)
    int nblk = gridDim.x;
    int orig = blockIdx.x;
    int q8 = nblk >> 3, r8 = nblk & 7;
    int xcd = orig & 7, lin = orig >> 3;
    int bid = (xcd < r8 ? xcd * (q8 + 1) : r8 * (q8 + 1) + (xcd - r8) * q8) + lin;
    int ti = (int)((sqrtf(8.0f * (float)bid + 1.0f) - 1.0f) * 0.5f);
    while ((ti + 1) * (ti + 2) / 2 <= bid) ++ti;
    while (ti * (ti + 1) / 2 > bid) --ti;
    int tj = bid - ti * (ti + 1) / 2;
    int r0 = ti * 64, c0 = tj * 64;
    int tid = threadIdx.x;
    int w = tid >> 6, l = tid & 63;
    int l15 = l & 15, lhi = l >> 4;
    const int kchu = D >> 4;                // 16B units per row-panel
    const i64x2* gx = (const i64x2*)xq;
    long long rpan = (long long)((r0 >> 4) + w) * kchu;
    long long cpan0 = (long long)(c0 >> 4) * kchu;
    f32x4 acc[4] = {};
    int nss = D >> 6;                       // supersteps (K=64 each)
    for (int s = 0; s < nss; ++s) {
        int uc = (s << 2) + lhi;            // unit = 4s + lhi
        i64x2 a = gx[(rpan + uc) * 16 + l15];
        i64x2 b[4];
#pragma unroll
        for (int j = 0; j < 4; ++j)
            b[j] = gx[(cpan0 + (long long)j * kchu + uc) * 16 + l15];
#pragma unroll
        for (int j = 0; j < 4; ++j) {
            acc[j] = __builtin_amdgcn_mfma_f32_16x16x32_fp8_fp8(a[0], b[j][0], acc[j], 0, 0, 0);
            acc[j] = __builtin_amdgcn_mfma_f32_16x16x32_fp8_fp8(a[1], b[j][1], acc[j], 0, 0, 0);
        }
    }
    // threshold on registers (squared); C layout (m89): col=l&15, row=lhi*4+r
    int trow = r0 + w * 16 + lhi * 4;
    float pnr[4];
#pragma unroll
    for (int r = 0; r < 4; ++r) {
        int t = trow + r;
        pnr[r] = (t < B) ? pn2[t] : 1.0f;
    }
    unsigned int hit = 0;
#pragma unroll
    for (int j = 0; j < 4; ++j) {
        int jj = c0 + j * 16 + l15;
        float pc = (jj < B) ? pn2[jj] : 1.0f;
#pragma unroll
        for (int r = 0; r < 4; ++r) {
            int t = trow + r;
            float a = acc[j][r];
            if (t < B && jj < B && t > jj && a > 0.0f &&
                a * a >= CHECK_T2 * pnr[r] * pc)
                hit = 1;
        }
    }
    if (hit) atomicOr(flag, 1u);
}

// ---- ragged-path kernels (any shape; correct but not perf-critical) ----
__global__ __launch_bounds__(256) void k_norms_row(const float* __restrict__ padrao,
                                                   int B, int D, float* __restrict__ pn2,
                                                   unsigned int* __restrict__ flag,
                                                   const int* __restrict__ n0p,
                                                   int force_flag) {
    __shared__ float red[4];
    int row = blockIdx.x;
    const float* r = padrao + (long long)row * D;
    float s = 0.0f;
    for (int k = threadIdx.x; k < D; k += 256) { float v = r[k]; s += v * v; }
    for (int off = 32; off > 0; off >>= 1) s += __shfl_down(s, off);
    int wid = threadIdx.x >> 6, lane = threadIdx.x & 63;
    if (lane == 0) red[wid] = s;
    __syncthreads();
    if (threadIdx.x == 0) {
        pn2[row] = fmaxf(red[0] + red[1] + red[2] + red[3], 1e-16f);
        if (row == 0 && (force_flag || (*n0p != 0))) atomicOr(flag, 1u);
    }
}

__global__ __launch_bounds__(256) void k_tricheck(const float* __restrict__ padrao,
                                                  const float* __restrict__ pn2,
                                                  int B, int D,
                                                  unsigned int* __restrict__ flag) {
    __shared__ float As[64][65];
    __shared__ float Bs[64][65];
    int bid = blockIdx.x;
    int ti = (int)((sqrtf(8.0f * (float)bid + 1.0f) - 1.0f) * 0.5f);
    while ((ti + 1) * (ti + 2) / 2 <= bid) ++ti;
    while (ti * (ti + 1) / 2 > bid) --ti;
    int tj = bid - ti * (ti + 1) / 2;
    int r0 = ti * 64, c0 = tj * 64;
    int tid = threadIdx.x;
    int ty = tid >> 4, tx = tid & 15;
    float acc[4][4] = {};
    for (int k0 = 0; k0 < D; k0 += 64) {
        for (int s = tid; s < 64 * 64; s += 256) {
            int rr = s >> 6, cc = s & 63;
            int gc = k0 + cc;
            int gr = r0 + rr;
            As[rr][cc] = (gr < B && gc < D) ? padrao[(long long)gr * D + gc] : 0.0f;
            gr = c0 + rr;
            Bs[rr][cc] = (gr < B && gc < D) ? padrao[(long long)gr * D + gc] : 0.0f;
        }
        __syncthreads();
        for (int kk = 0; kk < 64; ++kk) {
            float a[4], b[4];
#pragma unroll
            for (int i = 0; i < 4; ++i) a[i] = As[ty * 4 + i][kk];
#pragma unroll
            for (int j = 0; j < 4; ++j) b[j] = Bs[tx * 4 + j][kk];
#pragma unroll
            for (int i = 0; i < 4; ++i)
#pragma unroll
                for (int j = 0; j < 4; ++j) acc[i][j] += a[i] * b[j];
        }
        __syncthreads();
    }
    unsigned int hit = 0;
    for (int i = 0; i < 4; ++i)
        for (int j = 0; j < 4; ++j) {
            int t = r0 + ty * 4 + i, jj = c0 + tx * 4 + j;
            if (t < B && jj < B && t > jj) {
                float a = acc[i][j];
                if (a > 0.0f && a * a >= CHECK_T2 * pn2[t] * pn2[jj]) hit = 1;
            }
        }
    if (hit) atomicOr(flag, 1u);
}

__global__ __launch_bounds__(256) void k_zero_s(float* __restrict__ out, long long n) {
    long long i = (long long)blockIdx.x * blockDim.x + threadIdx.x;
    long long stride = (long long)gridDim.x * blockDim.x;
    for (; i < n; i += stride) out[i] = 0.0f;
}

// ------- kernel 3: exact sequential fallback (runs only if flag set) -------
__global__ __launch_bounds__(1024) void k_fallback(
    const float* __restrict__ padrao, const float* __restrict__ erro,
    const float* __restrict__ protos0, const float* __restrict__ forca0,
    const int* __restrict__ n0p, const float* __restrict__ gainp,
    float* __restrict__ out, const float* __restrict__ pn2_arr,
    float* __restrict__ wprotos, float* __restrict__ wforca,
    float* __restrict__ wprotn, const unsigned int* __restrict__ flag,
    int runnable, int B, int D, int P) {
    if (!runnable) return;
    if (*flag == 0) return;
    const int tid = threadIdx.x;
    const int NT = blockDim.x;
    __shared__ float rv[1024];
    __shared__ int ri[1024];
    for (long long i = tid; i < (long long)P * D; i += NT) wprotos[i] = protos0[i];
    for (int i = tid; i < P; i += NT) wforca[i] = forca0[i];
    __syncthreads();
    for (int j = tid; j < P; j += NT) {
        const float* r = wprotos + (long long)j * D;
        float s = 0.0f;
        for (int k = 0; k < D; ++k) s += r[k] * r[k];
        wprotn[j] = fmaxf(sqrtf(s), EPSV);
    }
    int n = *n0p;
    float gain = *gainp;
    __syncthreads();
    for (int t = 0; t < B; ++t) {
        const float* p = padrao + (long long)t * D;
        float pn = fmaxf(sqrtf(pn2_arr[t]), EPSV);
        float best = -INFINITY; int bidx = 0;
        for (int j = tid; j < n; j += NT) {
            const float* r = wprotos + (long long)j * D;
            float d = 0.0f;
            for (int k = 0; k < D; ++k) d += r[k] * p[k];
            float sim = d / (wprotn[j] * pn);
            if (sim > best) { best = sim; bidx = j; }
        }
        rv[tid] = best; ri[tid] = bidx;
        __syncthreads();
        for (int off = NT >> 1; off > 0; off >>= 1) {
            if (tid < off) {
                float ov = rv[tid + off]; int oi = ri[tid + off];
                if (ov > rv[tid] || (ov == rv[tid] && oi < ri[tid])) { rv[tid] = ov; ri[tid] = oi; }
            }
            __syncthreads();
        }
        float max_sim = rv[0]; int idx = ri[0];
        __syncthreads();
        float err = erro[t];
        bool is_empty = (n == 0);
        bool do_reinf = (!is_empty) && (max_sim >= LIMIAR_SIM);
        bool do_create = is_empty || ((!do_reinf) && ((err > LIMIAR_NOVO) || (n < P)));
        if (do_create) {
            int cidx = n;
            if (n >= P) {
                float bv = INFINITY; int bi = 0;
                for (int j = tid; j < P; j += NT) {
                    float f = wforca[j];
                    if (f < bv) { bv = f; bi = j; }
                }
                rv[tid] = bv; ri[tid] = bi;
                __syncthreads();
                for (int off = NT >> 1; off > 0; off >>= 1) {
                    if (tid < off) {
                        float ov = rv[tid + off]; int oi = ri[tid + off];
                        if (ov < rv[tid] || (ov == rv[tid] && oi < ri[tid])) { rv[tid] = ov; ri[tid] = oi; }
                    }
                    __syncthreads();
                }
                cidx = ri[0];
                __syncthreads();
            }
            float* dst = wprotos + (long long)cidx * D;
            float* o = out + (long long)t * D;
            for (int k = tid; k < D; k += NT) { dst[k] = p[k]; o[k] = 0.0f; }
            if (tid == 0) { wforca[cidx] = 1.0f; wprotn[cidx] = pn; }
            if (n < P) n = n + 1;
        } else if (do_reinf) {
            float* dst = wprotos + (long long)idx * D;
            float fr_new = wforca[idx] + LR;
            float* o = out + (long long)t * D;
            float s2 = 0.0f;
            for (int k = tid; k < D; k += NT) {
                float np_ = (1.0f - LR) * dst[k] + LR * p[k];
                dst[k] = np_;
                o[k] = (np_ - p[k]) * fr_new * gain;
                s2 += np_ * np_;
            }
            rv[tid] = s2;
            __syncthreads();
            for (int off = NT >> 1; off > 0; off >>= 1) {
                if (tid < off) rv[tid] += rv[tid + off];
                __syncthreads();
            }
            if (tid == 0) { wforca[idx] = fr_new; wprotn[idx] = fmaxf(sqrtf(rv[0]), EPSV); }
        } else {
            const float* src = wprotos + (long long)idx * D;
            float fr = wforca[idx];
            float* o = out + (long long)t * D;
            for (int k = tid; k < D; k += NT) o[k] = (src[k] - p[k]) * fr * gain;
        }
        __syncthreads();
    }
}

extern "C" void kernel_launch(void* const* d_in, const int* in_sizes, int n_in,
                              void* d_out, int out_size, void* d_ws, size_t ws_size,
                              hipStream_t stream) {
    const float* padrao  = (const float*)d_in[0];
    const float* erro    = (const float*)d_in[1];
    const float* protos0 = (const float*)d_in[2];
    const float* forca0  = (const float*)d_in[3];
    const int*   n0p     = (const int*)d_in[5];
    const float* gainp   = (const float*)d_in[6];
    const int B = in_sizes[1];
    const int D = (B > 0) ? in_sizes[0] / B : 0;
    const int P = in_sizes[3];

    char* ws = (char*)d_ws;
    unsigned int* flag = (unsigned int*)ws;
    float* pn2 = (float*)(ws + 64);
    size_t off_xq = ((64 + (size_t)B * 4) + 63) & ~(size_t)63;
    unsigned int* xq = (unsigned int*)(ws + off_xq);
    size_t off_protos = (off_xq + (size_t)B * (size_t)D + 63) & ~(size_t)63;  // fp8: B*D bytes
    float* wprotos = (float*)(ws + off_protos);
    size_t off_forca = off_protos + (size_t)P * (size_t)D * 4;
    float* wforca = (float*)(ws + off_forca);
    size_t off_protn = off_forca + (size_t)P * 4;
    float* wprotn = (float*)(ws + off_protn);
    size_t need_total = off_protn + (size_t)P * 4;
    size_t need_fast = off_xq + (size_t)B * (size_t)D;

    int runnable = (ws_size >= need_total) ? 1 : 0;
    int force_flag = (B > P) ? 1 : 0;
    int use_mfma = ((B % 64) == 0) && (D == 1024) && (ws_size >= need_fast)
                   && ((long long)out_size == (long long)B * D);

    int nT = (B + 63) / 64;
    int nblk = nT * (nT + 1) / 2;
    long long outN = (long long)out_size;

    // zero flag + pn2 (prep accumulates into pn2 via atomicAdd)
    hipMemsetAsync(ws, 0, 64 + (size_t)B * 4, stream);

    if (use_mfma) {
        k_prep_chunk<<<(B / 16) * 4, 256, 0, stream>>>(padrao, B, pn2, xq,
                                                       (f32x4*)d_out, flag, n0p, force_flag);
        k_trimain<<<nblk, 256, 0, stream>>>(xq, pn2, B, D, flag);
    } else {
        k_norms_row<<<B, 256, 0, stream>>>(padrao, B, D, pn2, flag, n0p, force_flag);
        k_tricheck<<<nblk, 256, 0, stream>>>(padrao, pn2, B, D, flag);
        int zb = (int)((outN + 255) / 256); if (zb > 2048) zb = 2048; if (zb < 1) zb = 1;
        k_zero_s<<<zb, 256, 0, stream>>>((float*)d_out, outN);
    }

    k_fallback<<<1, 1024, 0, stream>>>(padrao, erro, protos0, forca0, n0p, gainp,
                                       (float*)d_out, pn2, wprotos, wforca, wprotn,
                                       flag, runnable, B, D, P);
}